// Round 24
// baseline (189.400 us; speedup 1.0000x reference)
//
#include <hip/hip_runtime.h>

#define N_INST   1000000
#define NBX      512
#define NBY      512
#define NB       (NBX * NBY)
#define NUM_CKSR 48
#define NUM_CE   96
#define K        4          // w[4] of the reference 5-tap is identically 0 (half = 1.5 exactly)

// R24: returning scattered atomics service at ~20 G/s (R12-R23 model). Cut their count:
// lut loses per-item reservation entirely -> 16 x-strip buckets with BLOCK-AGGREGATED
// reservation (<=16 returning atomics per block, 62K total vs 714K). Strip histograms
// (u10 fixed-point, R16-proven numerics) built privately in LDS by 256 blocks, merged
// exactly. ff path unchanged (381K atomics ~= 19us floor). tile does ff only.
#define FTX   16
#define FTY   8
#define TGX   (NBX / FTX)   // 32
#define TGY   (NBY / FTY)   // 64
#define NFT   (TGX * TGY)   // 2048
#define SUB   8             // ff sub-buckets by blockIdx&7 (R13)
#define CAPF  48            // per sub-bucket; ff mean 14.3 (dup 1.633)
#define RS    145           // 48 ck + 96 ce + pad (odd stride, conflict-free)
#define ACCW  (FTX * FTY * RS)      // 18560 words

// Lut strips: 16 strips of 32 x-bins, keyed by lox=floor(px-1.5) (max(lox,0)>>5).
// Cells reach x in [32s, 32s+34] -> dilated width 35.
#define NSTRIP 16
#define SCAP   49152        // per strip; mean 44.6K, +22 sigma
#define NCOPY  16           // histogram copies per strip (256 blocks total)
#define SW     35
#define SH     512
#define HW     (SW * SH)    // 17920 words = 71680 B LDS

#define CSTRIDE 16          // one cursor per 64B line (R5)

// Constants folded in DOUBLE then rounded once to f32 (matches JAX): half = 1.5f exactly.
#define KHALF  ((float)(2.5 * 0.6))
#define KDENOM ((float)(0.6 * 1.4142135623730951))

__device__ __forceinline__ void axis_weights4(float pos, int nbins, int& lo_out, float w[K]) {
    float wlo = pos - KHALF;
    float whi = pos + KHALF;
    int lo_bin = (int)floorf(wlo);
    lo_out = lo_bin;
    float phi[K + 1];
#pragma unroll
    for (int k = 0; k <= K; ++k) {
        float e = (float)(lo_bin + k);
        float ec = fminf(fmaxf(e, wlo), whi);
        phi[k] = 0.5f * (1.f + erff((ec - pos) / KDENOM));
    }
    float wsum = 0.f;
#pragma unroll
    for (int k = 0; k < K; ++k) {
        int b = lo_bin + k;
        float ww = phi[k + 1] - phi[k];
        if (b < 0 || b >= nbins) ww = 0.f;
        w[k] = ww;
        wsum += ww;
    }
    float d = wsum + 1e-12f;
#pragma unroll
    for (int k = 0; k < K; ++k) w[k] = w[k] / d;   // division, as in reference
}

__device__ __forceinline__ unsigned q10(float w) {   // u10 (lut path only; no ceil -> safe)
    return min(1023u, (unsigned)rintf(w * 1024.f));
}

// Pass 1: lut -> (px,py) to strip bucket via block-aggregated reservation (no erf!);
// ff -> erf + exact-f32 SoA entries to dilated tile sub-buckets (unchanged).
__global__ void __launch_bounds__(256) classify_kernel(
        const float* __restrict__ pos,
        const int* __restrict__ luts,
        const int* __restrict__ ffs,
        const int* __restrict__ ctrl,
        int* __restrict__ strip_cur,      // [NSTRIP*CSTRIDE] zeroed
        int* __restrict__ ff_cur,         // [NFT*SUB*CSTRIDE] zeroed
        float2* __restrict__ stripb,      // [NSTRIP][SCAP]
        float4* __restrict__ ffwx,        // [NFT*SUB*CAPF]
        float4* __restrict__ ffwy,
        unsigned* __restrict__ ffmeta) {
    __shared__ int scount[NSTRIP], sbase[NSTRIP];
    int tid = threadIdx.x;
    int i = blockIdx.x * blockDim.x + tid;
    int sb = blockIdx.x & (SUB - 1);

    bool valid = i < N_INST;
    bool is_lut = false, is_ff = false;
    float px = 0.f, py = 0.f;
    if (valid) {
        is_lut = luts[i] > 0;
        is_ff  = !is_lut && (ffs[i] > 0);
        if (is_lut || is_ff) { px = pos[2 * i]; py = pos[2 * i + 1]; }
    }

    if (tid < NSTRIP) scount[tid] = 0;
    __syncthreads();

    int s = 0, myrank = 0;
    if (is_lut) {
        int lox = (int)floorf(px - KHALF);
        s = max(lox, 0) >> 5;
        myrank = atomicAdd(&scount[s], 1);            // LDS returning atomic (cheap)
    }
    __syncthreads();
    if (tid < NSTRIP && scount[tid] > 0)
        sbase[tid] = atomicAdd(&strip_cur[tid * CSTRIDE], scount[tid]);   // <=16 global
    __syncthreads();

    if (is_lut) {
        int slot = sbase[s] + myrank;
        if (slot < SCAP) stripb[(size_t)s * SCAP + slot] = make_float2(px, py);
        return;
    }
    if (!is_ff) return;

    int lox, loy;
    float wx[K], wy[K];
    axis_weights4(px, NBX, lox, wx);
    axis_weights4(py, NBY, loy, wy);
    float4 w1 = make_float4(wx[0], wx[1], wx[2], wx[3]);
    float4 w2 = make_float4(wy[0], wy[1], wy[2], wy[3]);
    unsigned ck   = (unsigned)ctrl[2 * i];
    unsigned ce48 = 48u + (unsigned)ctrl[2 * i + 1];
    int tx0 = max(lox, 0) >> 4, tx1 = min(lox + 3, NBX - 1) >> 4;
    int ty0 = max(loy, 0) >> 3, ty1 = min(loy + 3, NBY - 1) >> 3;
    for (int tx = tx0; tx <= tx1; ++tx) {
        for (int ty = ty0; ty <= ty1; ++ty) {
            unsigned cx = (unsigned)(lox - tx * FTX + 4);   // [1,19]
            unsigned cy = (unsigned)(loy - ty * FTY + 4);   // [1,11]
            int sbk = (tx * TGY + ty) * SUB + sb;
            int slot = atomicAdd(&ff_cur[sbk * CSTRIDE], 1);
            if (slot < CAPF) {
                size_t idx = (size_t)sbk * CAPF + slot;
                ffwx[idx] = w1;
                ffwy[idx] = w2;
                ffmeta[idx] = ck | (ce48 << 6) | (cx << 14) | (cy << 19);
            }
        }
    }
}

// Pass 2a: per-copy strip histogram (erf recomputed; u10 fixed-point 2^20; plain stores).
__global__ void __launch_bounds__(1024) strip_kernel(
        const float2* __restrict__ stripb,
        const int* __restrict__ strip_cur,
        unsigned* __restrict__ stripg) {   // [NSTRIP*NCOPY][HW]
    __shared__ unsigned hist[HW];
    int blk = blockIdx.x;
    int s = blk >> 4, c = blk & (NCOPY - 1);
    int tid = threadIdx.x;

    for (int j = tid; j < HW; j += 1024) hist[j] = 0u;
    __syncthreads();

    int cnt = min(strip_cur[s * CSTRIDE], SCAP);
    int chunk = (cnt + NCOPY - 1) >> 4;
    int e0 = c * chunk, e1 = min(cnt, e0 + chunk);
    int x0 = 32 * s;
    for (int e = e0 + tid; e < e1; e += 1024) {
        float2 p = stripb[(size_t)s * SCAP + e];
        int lox, loy;
        float wx[K], wy[K];
        axis_weights4(p.x, NBX, lox, wx);
        axis_weights4(p.y, NBY, loy, wy);
        unsigned qx[4] = { q10(wx[0]), q10(wx[1]), q10(wx[2]), q10(wx[3]) };
        unsigned qy[4] = { q10(wy[0]), q10(wy[1]), q10(wy[2]), q10(wy[3]) };
#pragma unroll
        for (int kx = 0; kx < K; ++kx) {
            int gxg = lox + kx;
            if ((unsigned)gxg >= NBX) continue;
            int gxl = gxg - x0;            // in [0,34] by bucketing invariant
#pragma unroll
            for (int ky = 0; ky < K; ++ky) {
                int gy = loy + ky;
                if ((unsigned)gy >= NBY) continue;
                atomicAdd(&hist[gxl * SH + gy], qx[kx] * qy[ky]);   // ds_add_u32
            }
        }
    }
    __syncthreads();

    unsigned* outp = stripg + (size_t)blk * HW;
    for (int j = tid; j < HW; j += 1024) outp[j] = hist[j];   // plain store
}

// Pass 2b: exact merge -> lut_dem. Bin (gx,gy): 16 copies of its strip, plus 16 of the
// left strip when rx<=2 (left-strip entries reach up to 32s+2).
__global__ void __launch_bounds__(256) merge_lut_kernel(
        const unsigned* __restrict__ stripg,
        float* __restrict__ lut_dem) {
    int bin = blockIdx.x * 256 + threadIdx.x;
    int gx = bin >> 9, gy = bin & 511;
    int s = gx >> 5, rx = gx & 31;
    unsigned sum = 0u;
#pragma unroll
    for (int c = 0; c < NCOPY; ++c)
        sum += stripg[(size_t)(s * NCOPY + c) * HW + rx * SH + gy];
    if (rx <= 2 && s > 0) {
#pragma unroll
        for (int c = 0; c < NCOPY; ++c)
            sum += stripg[(size_t)((s - 1) * NCOPY + c) * HW + (rx + 32) * SH + gy];
    }
    lut_dem[bin] = (float)sum * (1.f / 1048576.f);
}

// Pass 3: ff-only tile (R16 minus lut): decode + ds_add_f32, ff_scale epilogue.
__global__ void __launch_bounds__(1024) tile_ff_kernel(
        const float4* __restrict__ ffwx,
        const float4* __restrict__ ffwy,
        const unsigned* __restrict__ ffmeta,
        const int* __restrict__ ff_cur,
        float* __restrict__ ff_scale) {
    __shared__ float acc[ACCW];
    __shared__ int cnt_s[SUB];
    __shared__ int fpre[SUB + 1];
    int t = blockIdx.x;
    int X0 = (t / TGY) * FTX;
    int Y0 = (t % TGY) * FTY;
    int tid = threadIdx.x;

    if (tid < SUB) cnt_s[tid] = min(ff_cur[(t * SUB + tid) * CSTRIDE], CAPF);
    for (int j = tid; j < ACCW; j += 1024) acc[j] = 0.f;
    __syncthreads();
    if (tid == 0) {
        int s = 0; fpre[0] = 0;
        for (int c = 0; c < SUB; ++c) { s += cnt_s[c]; fpre[c + 1] = s; }
    }
    __syncthreads();

    int ftot = fpre[SUB];
    for (int e = tid; e < ftot; e += 1024) {
        int c = 0;
#pragma unroll
        for (int k = 1; k < SUB; ++k) c += (e >= fpre[k]);
        size_t idx = ((size_t)t * SUB + c) * CAPF + (e - fpre[c]);
        float4 a = ffwx[idx];
        float4 b = ffwy[idx];
        unsigned m = ffmeta[idx];
        float fx[4] = { a.x, a.y, a.z, a.w };
        float fy[4] = { b.x, b.y, b.z, b.w };
        int ck   = (int)(m & 63u);
        int ce48 = (int)((m >> 6) & 255u);
        int cx   = (int)((m >> 14) & 31u) - 4;
        int cy   = (int)((m >> 19) & 15u) - 4;
#pragma unroll
        for (int kx = 0; kx < K; ++kx) {
            int gx = cx + kx;
            if ((unsigned)gx >= FTX) continue;
            float wv = fx[kx];
#pragma unroll
            for (int ky = 0; ky < K; ++ky) {
                int gy = cy + ky;
                if ((unsigned)gy >= FTY) continue;
                float w2 = wv * fy[ky];
                if (w2 != 0.f) {
                    float* row = acc + (gx * FTY + gy) * RS;
                    unsafeAtomicAdd(row + ck, w2);     // ds_add_f32
                    unsafeAtomicAdd(row + ce48, w2);
                }
            }
        }
    }
    __syncthreads();

    if (tid < 512) {
        int lb = tid >> 2, q = tid & 3;
        const float* row = acc + lb * RS;
        float raw = 0.f, effck = 0.f, effce = 0.f;
#pragma unroll
        for (int c = 0; c < 12; ++c) {
            float v = row[12 * q + c];
            raw += v;
            effck += ceilf(v * 0.125f);
        }
#pragma unroll
        for (int c = 0; c < 24; ++c) {
            effce += ceilf(row[48 + 24 * q + c] * 0.25f);
        }
        raw   += __shfl_xor(raw, 1);   raw   += __shfl_xor(raw, 2);
        effck += __shfl_xor(effck, 1); effck += __shfl_xor(effck, 2);
        effce += __shfl_xor(effce, 1); effce += __shfl_xor(effce, 2);
        if (q == 0) {
            float eff = fmaxf(effck * 8.f, effce * 4.f);
            int gx = X0 + (lb >> 3);
            int gy = Y0 + (lb & 7);
            ff_scale[gx * NBY + gy] = fmaxf(eff / fmaxf(raw, 1e-6f), 1.f);
        }
    }
}

// Pass 4: per-instance gather; recomputes exact f32 weights from pos (R16).
__global__ void __launch_bounds__(256) area_kernel(
        const float* __restrict__ pos,
        const int* __restrict__ luts,
        const int* __restrict__ ffs,
        const float* __restrict__ lut_dem,
        const float* __restrict__ ff_scale,
        float* __restrict__ out) {
    int i = blockIdx.x * blockDim.x + threadIdx.x;
    if (i >= N_INST) return;
    bool is_lut = luts[i] > 0;
    bool is_ff  = (ffs[i] > 0) && !is_lut;
    if (!is_lut && !is_ff) { out[i] = 0.f; return; }

    float px = pos[2 * i], py = pos[2 * i + 1];
    int lox, loy;
    float wx[K], wy[K];
    axis_weights4(px, NBX, lox, wx);
    axis_weights4(py, NBY, loy, wy);

    const float* tbl = is_lut ? lut_dem : ff_scale;
    float acc = 0.f;
#pragma unroll
    for (int kx = 0; kx < K; ++kx) {
        int gx = min(max(lox + kx, 0), NBX - 1);
#pragma unroll
        for (int ky = 0; ky < K; ++ky) {
            int gy = min(max(loy + ky, 0), NBY - 1);
            float w2 = wx[kx] * wy[ky];
            float v = tbl[gx * NBY + gy];
            float sc = is_lut ? fmaxf(v * 0.0625f, 1.f) : v;
            acc += w2 * sc;
        }
    }
    out[i] = acc;
}

extern "C" void kernel_launch(void* const* d_in, const int* in_sizes, int n_in,
                              void* d_out, int out_size, void* d_ws, size_t ws_size,
                              hipStream_t stream) {
    const float* pos  = (const float*)d_in[0];
    const int*   luts = (const int*)d_in[1];
    const int*   ffs  = (const int*)d_in[2];
    const int*   ctrl = (const int*)d_in[3];
    float* out = (float*)d_out;

    // ws: strip_cur (1KB) | ff_cur (1MB) | lut_dem (1MB) | ff_scale (1MB)
    //     | stripg (17.9MB) | stripb (6.3MB) | ffwx (12.6MB) | ffwy (12.6MB) | ffmeta (3.1MB)
    int*      strip_cur = (int*)d_ws;
    int*      ff_cur    = strip_cur + NSTRIP * CSTRIDE;
    float*    lut_dem   = (float*)(ff_cur + (size_t)NFT * SUB * CSTRIDE);
    float*    ff_scale  = lut_dem + NB;
    unsigned* stripg    = (unsigned*)(ff_scale + NB);
    float2*   stripb    = (float2*)(stripg + (size_t)NSTRIP * NCOPY * HW);
    float4*   ffwx      = (float4*)(stripb + (size_t)NSTRIP * SCAP);
    float4*   ffwy      = ffwx + (size_t)NFT * SUB * CAPF;
    unsigned* ffmeta    = (unsigned*)(ffwy + (size_t)NFT * SUB * CAPF);

    // Zero strip_cur + ff_cur (contiguous ~1MB). lut_dem/ff_scale fully written.
    hipMemsetAsync(d_ws, 0, (size_t)(NSTRIP * CSTRIDE + NFT * SUB * CSTRIDE) * sizeof(int), stream);

    dim3 blk(256);
    dim3 grdI((N_INST + 255) / 256);

    classify_kernel<<<grdI, blk, 0, stream>>>(pos, luts, ffs, ctrl,
                                              strip_cur, ff_cur, stripb, ffwx, ffwy, ffmeta);
    strip_kernel<<<NSTRIP * NCOPY, dim3(1024), 0, stream>>>(stripb, strip_cur, stripg);
    merge_lut_kernel<<<NB / 256, blk, 0, stream>>>(stripg, lut_dem);
    tile_ff_kernel<<<NFT, dim3(1024), 0, stream>>>(ffwx, ffwy, ffmeta, ff_cur, ff_scale);
    area_kernel<<<grdI, blk, 0, stream>>>(pos, luts, ffs, lut_dem, ff_scale, out);
}